// Round 1
// baseline (523.557 us; speedup 1.0000x reference)
//
#include <hip/hip_runtime.h>
#include <hip/hip_bf16.h>
#include <math.h>

#define S_LEN 2048
#define DIM   128
#define NHEAD 16
#define BQ    62          // conv-output rows per workgroup
#define BK    64          // k-tile width
#define SCALE 0.08838834764831845f  // 1/sqrt(128)

typedef __attribute__((ext_vector_type(8))) short bf16x8;
typedef __attribute__((ext_vector_type(4))) float f32x4;

__device__ inline short f2bf(float f) {
  union { float f; unsigned u; } v; v.f = f;
  unsigned r = v.u + 0x7fffu + ((v.u >> 16) & 1u);
  return (short)(r >> 16);
}

// One workgroup = one (head, q-tile). Raw score tile rows [q0-2, q0+62) (64 rows,
// 4 MFMA row-blocks, zero waste), conv output rows [q0, q0+62).
// Lag pipeline: raw tile t computed, then conv/softmax/PV for tile t-1 (right
// halo = col 0 of tile t; left halo = saved col 63 of tile t-2; final tile's
// right halo is provably zero since scores above diagonal are 0 pre-conv).
__global__ __launch_bounds__(256, 2)
void convattn_kernel(const float* __restrict__ Q, const float* __restrict__ K,
                     const float* __restrict__ V, const float* __restrict__ W,
                     float* __restrict__ Out) {
  __shared__ __align__(16) short Kt[64][136];      // K tile, bf16, row=kv col=d (pad 8)
  __shared__ __align__(16) short Vt[128][72];      // V tile transposed: [d][kv] (pad 8)
  __shared__ __align__(16) float rawS[2][64][68];  // raw scores, fp32, dbl-buffered
  __shared__ __align__(16) short P[64][72];        // probs bf16 (pad 8)
  __shared__ float haloL[64];                      // col k0-1 of current conv tile
  __shared__ float mrow[64], lrow[64], alphaRow[64];

  const int h  = blockIdx.y;
  const int qt = blockIdx.x;
  const int q0 = qt * BQ;
  const int qr0 = q0 - 2;
  const int q_cap = min(q0 + BQ - 1, S_LEN - 1);
  const int T = q_cap / BK + 1;

  const int tid  = threadIdx.x;
  const int wid  = tid >> 6;
  const int lane = tid & 63;
  const int lm   = lane & 15;   // MFMA m/n index
  const int lg   = lane >> 4;   // MFMA k-group

  const float* Qh = Q + (size_t)h * S_LEN * DIM;
  const float* Kh = K + (size_t)h * S_LEN * DIM;
  const float* Vh = V + (size_t)h * S_LEN * DIM;
  float* Oh = Out + (size_t)h * S_LEN * DIM;

  float wk[9];
  #pragma unroll
  for (int i = 0; i < 9; ++i) wk[i] = W[h * 9 + i];

  // ---- Q fragments (A operand), hoisted: rows qr0 + wid*16 + lm, all of D ----
  bf16x8 qf[4];
  {
    int qrow = qr0 + wid * 16 + lm;
    int qc = qrow < 0 ? 0 : (qrow >= S_LEN ? S_LEN - 1 : qrow);
    const float* qp = Qh + (size_t)qc * DIM;
    #pragma unroll
    for (int kk = 0; kk < 4; ++kk) {
      int d0 = kk * 32 + lg * 8;
      float4 a = *(const float4*)(qp + d0);
      float4 b = *(const float4*)(qp + d0 + 4);
      bf16x8 f;
      f[0]=f2bf(a.x); f[1]=f2bf(a.y); f[2]=f2bf(a.z); f[3]=f2bf(a.w);
      f[4]=f2bf(b.x); f[5]=f2bf(b.y); f[6]=f2bf(b.z); f[7]=f2bf(b.w);
      qf[kk] = f;
    }
  }

  // ---- init persistent state ----
  if (tid < 64) { mrow[tid] = -INFINITY; lrow[tid] = 0.f; alphaRow[tid] = 1.f; haloL[tid] = 0.f; }
  for (int idx = tid; idx < 64 * 72; idx += 256) ((short*)P)[idx] = 0;

  f32x4 oacc[8];
  const f32x4 zero4 = {0.f, 0.f, 0.f, 0.f};
  #pragma unroll
  for (int cb = 0; cb < 8; ++cb) oacc[cb] = zero4;

  for (int t = 0; t <= T; ++t) {
    __syncthreads();  // protect Kt/Vt/alphaRow reuse from previous iteration
    // ---- Phase A: stage K tile t, V tile t-1 (bf16, V transposed) ----
    if (t < T) {
      int k0 = t * BK;
      int r = tid >> 2, dc = (tid & 3) * 32;
      const float* kp = Kh + (size_t)(k0 + r) * DIM + dc;
      #pragma unroll
      for (int j = 0; j < 32; j += 4) {
        float4 v = *(const float4*)(kp + j);
        Kt[r][dc + j]     = f2bf(v.x);
        Kt[r][dc + j + 1] = f2bf(v.y);
        Kt[r][dc + j + 2] = f2bf(v.z);
        Kt[r][dc + j + 3] = f2bf(v.w);
      }
    }
    if (t > 0) {
      int kv0 = (t - 1) * BK;
      int r = tid >> 2, dc = (tid & 3) * 32;
      const float* vp = Vh + (size_t)(kv0 + r) * DIM + dc;
      #pragma unroll
      for (int j = 0; j < 32; j += 4) {
        float4 v = *(const float4*)(vp + j);
        Vt[dc + j][r]     = f2bf(v.x);
        Vt[dc + j + 1][r] = f2bf(v.y);
        Vt[dc + j + 2][r] = f2bf(v.z);
        Vt[dc + j + 3][r] = f2bf(v.w);
      }
    }
    __syncthreads();
    // ---- Phase B: QK^T MFMA -> masked raw tile t ----
    if (t < T) {
      int k0 = t * BK;
      f32x4 sacc[4];
      #pragma unroll
      for (int cb = 0; cb < 4; ++cb) sacc[cb] = zero4;
      #pragma unroll
      for (int kk = 0; kk < 4; ++kk) {
        #pragma unroll
        for (int cb = 0; cb < 4; ++cb) {
          bf16x8 bf = *(const bf16x8*)&Kt[cb * 16 + lm][kk * 32 + lg * 8];
          sacc[cb] = __builtin_amdgcn_mfma_f32_16x16x32_bf16(qf[kk], bf, sacc[cb], 0, 0, 0);
        }
      }
      const int buf = t & 1;
      #pragma unroll
      for (int cb = 0; cb < 4; ++cb) {
        #pragma unroll
        for (int i = 0; i < 4; ++i) {
          int rr = wid * 16 + lg * 4 + i;       // C/D layout: row = 4*(l>>4)+i
          int cc = cb * 16 + lm;                //             col = l&15
          rawS[buf][rr][cc] = ((k0 + cc) <= (qr0 + rr)) ? sacc[cb][i] * SCALE : 0.f;
        }
      }
    }
    __syncthreads();
    // ---- Phase C: conv + online softmax for tile t-1; then rescale + PV ----
    if (t > 0) {
      const int tp = t - 1;
      const int pb = tp & 1, nb = pb ^ 1;
      const int c0p = tp * BK;
      const bool haveRight = (t < T);
      for (int r = 2 + wid; r < 64; r += 4) {   // one wave owns each row
        int q = qr0 + r;
        if (q > q_cap) continue;                // uniform per wave
        int c = lane;
        float acc2 = 0.f;
        #pragma unroll
        for (int i = 0; i < 3; ++i) {
          int rr = r - 2 + i;
          float aL = (c == 0)  ? haloL[rr] : rawS[pb][rr][c - 1];
          float aM = rawS[pb][rr][c];
          float aR = (c == 63) ? (haveRight ? rawS[nb][rr][0] : 0.f) : rawS[pb][rr][c + 1];
          acc2 += wk[3 * i] * aL + wk[3 * i + 1] * aM + wk[3 * i + 2] * aR;
        }
        int kc = c0p + c;
        bool valid = (kc <= q);
        float sv = valid ? acc2 : -INFINITY;
        float mx = sv;
        #pragma unroll
        for (int off = 32; off >= 1; off >>= 1) mx = fmaxf(mx, __shfl_xor(mx, off));
        float mo = mrow[r];
        float mn = fmaxf(mo, mx);
        float al = __expf(mo - mn);             // mo=-inf -> 0
        float p  = valid ? __expf(acc2 - mn) : 0.f;
        float ps = p;
        #pragma unroll
        for (int off = 32; off >= 1; off >>= 1) ps += __shfl_xor(ps, off);
        P[r][c] = f2bf(p);
        if (lane == 0) { mrow[r] = mn; lrow[r] = al * lrow[r] + ps; alphaRow[r] = al; }
      }
      __syncthreads();
      if (tid < 64) haloL[tid] = rawS[pb][tid][63];   // left halo for next tile
      #pragma unroll
      for (int i = 0; i < 4; ++i) {
        float a = alphaRow[wid * 16 + lg * 4 + i];
        #pragma unroll
        for (int cb = 0; cb < 8; ++cb) oacc[cb][i] *= a;
      }
      #pragma unroll
      for (int kk = 0; kk < 2; ++kk) {
        bf16x8 pf = *(const bf16x8*)&P[wid * 16 + lm][kk * 32 + lg * 8];
        #pragma unroll
        for (int cb = 0; cb < 8; ++cb) {
          bf16x8 vf = *(const bf16x8*)&Vt[cb * 16 + lm][kk * 32 + lg * 8];
          oacc[cb] = __builtin_amdgcn_mfma_f32_16x16x32_bf16(pf, vf, oacc[cb], 0, 0, 0);
        }
      }
    }
  }

  __syncthreads();
  // ---- epilogue: normalize and store ----
  #pragma unroll
  for (int i = 0; i < 4; ++i) {
    int rr = wid * 16 + lg * 4 + i;
    int q = qr0 + rr;
    if (rr >= 2 && q <= q_cap) {
      float inv = 1.f / lrow[rr];
      #pragma unroll
      for (int cb = 0; cb < 8; ++cb) {
        Oh[(size_t)q * DIM + cb * 16 + lm] = oacc[cb][i] * inv;
      }
    }
  }
}

extern "C" void kernel_launch(void* const* d_in, const int* in_sizes, int n_in,
                              void* d_out, int out_size, void* d_ws, size_t ws_size,
                              hipStream_t stream) {
  const float* Q = (const float*)d_in[0];
  const float* K = (const float*)d_in[1];
  const float* V = (const float*)d_in[2];
  const float* W = (const float*)d_in[3];
  float* Out = (float*)d_out;
  const int NQT = (S_LEN + BQ - 1) / BQ;   // 34
  dim3 grid(NQT, NHEAD);
  convattn_kernel<<<grid, 256, 0, stream>>>(Q, K, V, W, Out);
}

// Round 2
// 187.711 us; speedup vs baseline: 2.7892x; 2.7892x over previous
//
#include <hip/hip_runtime.h>
#include <hip/hip_bf16.h>
#include <math.h>

#define S_LEN 2048
#define DIM   128
#define NHEAD 16
#define BQ    62          // conv-output rows per workgroup
#define BK    64          // k-tile width
#define SCALE 0.08838834764831845f  // 1/sqrt(128)

typedef __attribute__((ext_vector_type(8))) short bf16x8;
typedef __attribute__((ext_vector_type(4))) float f32x4;

__device__ inline short f2bf(float f) {
  union { float f; unsigned u; } v; v.f = f;
  unsigned r = v.u + 0x7fffu + ((v.u >> 16) & 1u);
  return (short)(r >> 16);
}

// One workgroup = one (head, q-tile). Raw score tile rows [q0-2, q0+62) (64 rows),
// conv output rows [q0, q0+62). Lag pipeline: raw tile t computed, then
// conv/softmax/PV for tile t-1 (right halo = col 0 of tile t; left halo = saved
// col 63 of tile t-2; final tile's right halo is provably zero since scores
// above the diagonal are 0 pre-conv).
// Phase C layout: lane = row (64 rows), wave = 16-col slice -> conv in registers,
// per-lane max/sum, tiny cross-wave LDS combine. No shuffle chains.
__global__ __launch_bounds__(256, 2)
void convattn_kernel(const float* __restrict__ Q, const float* __restrict__ K,
                     const float* __restrict__ V, const float* __restrict__ W,
                     float* __restrict__ Out) {
  __shared__ __align__(16) short Kt[64][136];      // K tile bf16 [kv][d] (stride 68 dw)
  __shared__ __align__(16) short Vt[128][68];      // V tile bf16 transposed [d][kv]
  __shared__ __align__(16) float rawS[2][64][67];  // raw scores fp32, odd stride
  __shared__ __align__(16) short P[64][66];        // probs bf16, odd-dw stride
  __shared__ float haloL[64];                      // col k0-1 of current conv tile
  __shared__ float mrow[64], lrow[64], alphaRow[64];
  __shared__ float pmax[4][64], psum[4][64];

  const int h  = blockIdx.y;
  const int qt = (gridDim.x - 1) - blockIdx.x;     // longest-first scheduling
  const int q0 = qt * BQ;
  const int qr0 = q0 - 2;
  const int q_cap = min(q0 + BQ - 1, S_LEN - 1);
  const int T = q_cap / BK + 1;

  const int tid  = threadIdx.x;
  const int wid  = tid >> 6;
  const int lane = tid & 63;
  const int lm   = lane & 15;   // MFMA m/n index
  const int lg   = lane >> 4;   // MFMA k-group

  const float* Qh = Q + (size_t)h * S_LEN * DIM;
  const float* Kh = K + (size_t)h * S_LEN * DIM;
  const float* Vh = V + (size_t)h * S_LEN * DIM;
  float* Oh = Out + (size_t)h * S_LEN * DIM;

  float wk[9];
  #pragma unroll
  for (int i = 0; i < 9; ++i) wk[i] = W[h * 9 + i];

  // ---- Q fragments (A operand), hoisted ----
  bf16x8 qf[4];
  {
    int qrow = qr0 + wid * 16 + lm;
    int qc = qrow < 0 ? 0 : (qrow >= S_LEN ? S_LEN - 1 : qrow);
    const float* qp = Qh + (size_t)qc * DIM;
    #pragma unroll
    for (int kk = 0; kk < 4; ++kk) {
      int d0 = kk * 32 + lg * 8;
      float4 a = *(const float4*)(qp + d0);
      float4 b = *(const float4*)(qp + d0 + 4);
      bf16x8 f;
      f[0]=f2bf(a.x); f[1]=f2bf(a.y); f[2]=f2bf(a.z); f[3]=f2bf(a.w);
      f[4]=f2bf(b.x); f[5]=f2bf(b.y); f[6]=f2bf(b.z); f[7]=f2bf(b.w);
      qf[kk] = f;
    }
  }

  if (tid < 64) { mrow[tid] = -INFINITY; lrow[tid] = 0.f; haloL[tid] = 0.f; }

  f32x4 oacc[8];
  const f32x4 zero4 = {0.f, 0.f, 0.f, 0.f};
  #pragma unroll
  for (int cb = 0; cb < 8; ++cb) oacc[cb] = zero4;

  for (int t = 0; t <= T; ++t) {
    __syncthreads();  // protect Kt/Vt reuse from previous iteration's PV
    // ---- Phase A: stage K tile t, V tile t-1 (bf16, V transposed) ----
    if (t < T) {
      int k0 = t * BK;
      int r = tid >> 2, dc = (tid & 3) * 32;
      const float* kp = Kh + (size_t)(k0 + r) * DIM + dc;
      #pragma unroll
      for (int j = 0; j < 32; j += 4) {
        float4 v = *(const float4*)(kp + j);
        Kt[r][dc + j]     = f2bf(v.x);
        Kt[r][dc + j + 1] = f2bf(v.y);
        Kt[r][dc + j + 2] = f2bf(v.z);
        Kt[r][dc + j + 3] = f2bf(v.w);
      }
    }
    if (t > 0) {
      int kv0 = (t - 1) * BK;
      int r = tid >> 2, dc = (tid & 3) * 32;
      const float* vp = Vh + (size_t)(kv0 + r) * DIM + dc;
      #pragma unroll
      for (int j = 0; j < 32; j += 4) {
        float4 v = *(const float4*)(vp + j);
        Vt[dc + j][r]     = f2bf(v.x);
        Vt[dc + j + 1][r] = f2bf(v.y);
        Vt[dc + j + 2][r] = f2bf(v.z);
        Vt[dc + j + 3][r] = f2bf(v.w);
      }
    }
    __syncthreads();
    // ---- Phase B: QK^T MFMA -> masked raw tile t ----
    if (t < T) {
      int k0 = t * BK;
      f32x4 sacc[4];
      #pragma unroll
      for (int cb = 0; cb < 4; ++cb) sacc[cb] = zero4;
      #pragma unroll
      for (int kk = 0; kk < 4; ++kk) {
        #pragma unroll
        for (int cb = 0; cb < 4; ++cb) {
          bf16x8 bf = *(const bf16x8*)&Kt[cb * 16 + lm][kk * 32 + lg * 8];
          sacc[cb] = __builtin_amdgcn_mfma_f32_16x16x32_bf16(qf[kk], bf, sacc[cb], 0, 0, 0);
        }
      }
      const int buf = t & 1;
      #pragma unroll
      for (int cb = 0; cb < 4; ++cb) {
        #pragma unroll
        for (int i = 0; i < 4; ++i) {
          int rr = wid * 16 + lg * 4 + i;       // C/D: row = 4*(l>>4)+i
          int cc = cb * 16 + lm;                //      col = l&15
          rawS[buf][rr][cc] = ((k0 + cc) <= (qr0 + rr)) ? sacc[cb][i] * SCALE : 0.f;
        }
      }
    }
    __syncthreads();
    // ---- Phase C: conv (lane=row, wave=16-col slice) + online softmax + PV ----
    if (t > 0) {
      const int tp = t - 1;
      const int pb = tp & 1, nb = pb ^ 1;
      const int c0p = tp * BK;
      const bool haveRight = (t < T);
      const int r = lane;
      const int c0 = wid * 16;
      const int q = qr0 + r;
      const bool rowvalid = (r >= 2) && (q <= q_cap);
      const int r0 = max(r - 2, 0), r1 = max(r - 1, 0);

      // register sliding-window conv over 16 cols
      float l0, l1, l2, m0, m1, m2;
      if (wid == 0) { l0 = haloL[r0]; l1 = haloL[r1]; l2 = haloL[r]; }
      else { l0 = rawS[pb][r0][c0 - 1]; l1 = rawS[pb][r1][c0 - 1]; l2 = rawS[pb][r][c0 - 1]; }
      m0 = rawS[pb][r0][c0]; m1 = rawS[pb][r1][c0]; m2 = rawS[pb][r][c0];

      float sv[16];
      float pm = -INFINITY;
      #pragma unroll
      for (int c = 0; c < 16; ++c) {
        float n0, n1, n2;
        if (c < 15) {
          n0 = rawS[pb][r0][c0 + c + 1]; n1 = rawS[pb][r1][c0 + c + 1]; n2 = rawS[pb][r][c0 + c + 1];
        } else if (wid < 3) {
          n0 = rawS[pb][r0][c0 + 16]; n1 = rawS[pb][r1][c0 + 16]; n2 = rawS[pb][r][c0 + 16];
        } else if (haveRight) {
          n0 = rawS[nb][r0][0]; n1 = rawS[nb][r1][0]; n2 = rawS[nb][r][0];
        } else {
          n0 = 0.f; n1 = 0.f; n2 = 0.f;
        }
        float cv = wk[0]*l0 + wk[1]*m0 + wk[2]*n0
                 + wk[3]*l1 + wk[4]*m1 + wk[5]*n1
                 + wk[6]*l2 + wk[7]*m2 + wk[8]*n2;
        bool v = rowvalid && ((c0p + c0 + c) <= q);
        sv[c] = v ? cv : -INFINITY;
        pm = fmaxf(pm, sv[c]);
        l0 = m0; m0 = n0; l1 = m1; m1 = n1; l2 = m2; m2 = n2;
      }
      pmax[wid][r] = pm;
      __syncthreads();
      float mx = fmaxf(fmaxf(pmax[0][r], pmax[1][r]), fmaxf(pmax[2][r], pmax[3][r]));
      float mo = mrow[r];
      float mn = fmaxf(mo, mx);
      float al = __expf(mo - mn);
      float ps = 0.f;
      #pragma unroll
      for (int c = 0; c < 16; ++c) {
        float p = __expf(sv[c] - mn);
        ps += p;
        P[r][c0 + c] = f2bf(p);
      }
      psum[wid][r] = ps;
      if (wid == 0) alphaRow[r] = al;
      __syncthreads();
      if (wid == 0) {
        mrow[r] = mn;
        lrow[r] = al * lrow[r] + (psum[0][r] + psum[1][r] + psum[2][r] + psum[3][r]);
      }
      if (wid == 1) haloL[r] = rawS[pb][r][63];
      // ---- rescale + PV MFMA ----
      #pragma unroll
      for (int i = 0; i < 4; ++i) {
        float a = alphaRow[wid * 16 + lg * 4 + i];
        #pragma unroll
        for (int cb = 0; cb < 8; ++cb) oacc[cb][i] *= a;
      }
      #pragma unroll
      for (int kk = 0; kk < 2; ++kk) {
        bf16x8 pf = *(const bf16x8*)&P[wid * 16 + lm][kk * 32 + lg * 8];
        #pragma unroll
        for (int cb = 0; cb < 8; ++cb) {
          bf16x8 vf = *(const bf16x8*)&Vt[cb * 16 + lm][kk * 32 + lg * 8];
          oacc[cb] = __builtin_amdgcn_mfma_f32_16x16x32_bf16(pf, vf, oacc[cb], 0, 0, 0);
        }
      }
    }
  }

  __syncthreads();
  // ---- epilogue: normalize and store ----
  #pragma unroll
  for (int i = 0; i < 4; ++i) {
    int rr = wid * 16 + lg * 4 + i;
    int q = qr0 + rr;
    if (rr >= 2 && q <= q_cap) {
      float inv = 1.f / lrow[rr];
      #pragma unroll
      for (int cb = 0; cb < 8; ++cb) {
        Oh[(size_t)q * DIM + cb * 16 + lm] = oacc[cb][i] * inv;
      }
    }
  }
}

extern "C" void kernel_launch(void* const* d_in, const int* in_sizes, int n_in,
                              void* d_out, int out_size, void* d_ws, size_t ws_size,
                              hipStream_t stream) {
  const float* Q = (const float*)d_in[0];
  const float* K = (const float*)d_in[1];
  const float* V = (const float*)d_in[2];
  const float* W = (const float*)d_in[3];
  float* Out = (float*)d_out;
  const int NQT = (S_LEN + BQ - 1) / BQ;   // 34
  dim3 grid(NQT, NHEAD);
  convattn_kernel<<<grid, 256, 0, stream>>>(Q, K, V, W, Out);
}